// Round 4
// baseline (70.251 us; speedup 1.0000x reference)
//
#include <hip/hip_runtime.h>
#include <hip/hip_bf16.h>
#include <math.h>

// Problem constants (match reference)
#define B 8
#define L 2048
#define H 2048
#define NA 8
#define NEG_INF (-1e30f)

#define XT 64          // column tiles (32 cols each)
#define COLS 32

__device__ __forceinline__ float sigf(float t) {
    return 1.0f / (1.0f + __expf(-t));
}

// Kernel 1 (action-deduped): Wyp[b,s,x] = partial_s of sum_h y[b,h]*weight[h,x]*sig(wa[a_b,h,x])
// Distinct actions are computed once; each (group, h-row) is processed exactly ONCE
// (not once per b), so wa traffic = ngroups*16MiB instead of B*16MiB.
// grid (XT, 8 slots) x 256 threads. Block (xt, s) takes slice s of the flattened
// (group, h) work list -> perfectly balanced for any action multiset.
// Thread (hg = t>>3, c4 = t&7); block-internal LDS tree reduce; no atomics/fences.
__global__ __launch_bounds__(256) void k_wy(
    const float* __restrict__ y, const int* __restrict__ actions,
    const float* __restrict__ weight, const float* __restrict__ wa,
    const float* __restrict__ bias, const float* __restrict__ ba,
    float* __restrict__ Wyp)
{
    const int xt = blockIdx.x;
    const int s  = blockIdx.y;           // slot 0..7
    const int x0 = xt * COLS;
    const int c4 = threadIdx.x & 7;
    const int hg = threadIdx.x >> 3;     // 0..31

    __shared__ float ylds[B * H];        // 64 KB; reused as reduce buffer after h-loop
    __shared__ int s_ga[8], s_gmask[8], s_ng;

    if (threadIdx.x == 0) {
        int acts[8];
        for (int b2 = 0; b2 < 8; ++b2) acts[b2] = actions[b2];
        int ng = 0;
        for (int b2 = 0; b2 < 8; ++b2) {
            bool isnew = true;
            for (int p = 0; p < b2; ++p) if (acts[p] == acts[b2]) isnew = false;
            if (isnew) {
                int m = 0;
                for (int q = 0; q < 8; ++q) if (acts[q] == acts[b2]) m |= 1 << q;
                s_ga[ng] = acts[b2]; s_gmask[ng] = m; ++ng;
            }
        }
        s_ng = ng;
    }
    // stage all B y-rows (y is only 64 KB, L3-resident)
    for (int i = threadIdx.x * 4; i < B * H; i += 1024)
        *(float4*)(ylds + i) = *(const float4*)(y + i);
    __syncthreads();

    const int ng     = s_ng;
    const int fStart = s * ng * (H / 8);       // slice of flattened (g,h) list
    const int fEnd   = fStart + ng * (H / 8);  // slice length = ng*256 rows

    float4 acc[8];
    #pragma unroll
    for (int b2 = 0; b2 < 8; ++b2) acc[b2] = make_float4(0.f, 0.f, 0.f, 0.f);

    for (int g = fStart / H; g * H < fEnd; ++g) {
        const int h0   = max(fStart - g * H, 0);
        const int h1   = min(fEnd - g * H, H);
        const int mask = __builtin_amdgcn_readfirstlane(s_gmask[g]);
        const int a    = __builtin_amdgcn_readfirstlane(s_ga[g]);
        const float* __restrict__ wp = weight + x0 + c4 * 4;
        const float* __restrict__ ap = wa + (size_t)a * H * H + x0 + c4 * 4;
        #pragma unroll 4
        for (int h = h0 + hg; h < h1; h += 32) {
            const float4 w4 = *(const float4*)(wp + (size_t)h * H);
            const float4 a4 = *(const float4*)(ap + (size_t)h * H);
            float4 s4;
            s4.x = w4.x * sigf(a4.x);
            s4.y = w4.y * sigf(a4.y);
            s4.z = w4.z * sigf(a4.z);
            s4.w = w4.w * sigf(a4.w);
            #pragma unroll
            for (int b2 = 0; b2 < 8; ++b2) {
                if (mask & (1 << b2)) {            // wave-uniform scalar branch
                    const float yv = ylds[b2 * H + h];
                    acc[b2].x += yv * s4.x;
                    acc[b2].y += yv * s4.y;
                    acc[b2].z += yv * s4.z;
                    acc[b2].w += yv * s4.w;
                }
            }
        }
    }

    __syncthreads();                       // y reads done; reuse ylds for reduction
    float4* red = (float4*)ylds;           // layout [b][hg][c4] -> ((b*32+hg)*8+c4), 32 KB
    #pragma unroll
    for (int b2 = 0; b2 < 8; ++b2) red[(b2 * 32 + hg) * 8 + c4] = acc[b2];
    __syncthreads();
    #pragma unroll
    for (int st = 16; st; st >>= 1) {
        if (hg < st) {
            #pragma unroll
            for (int b2 = 0; b2 < 8; ++b2) {
                float4 o = red[(b2 * 32 + hg + st) * 8 + c4];
                float4 m2 = red[(b2 * 32 + hg) * 8 + c4];
                m2.x += o.x; m2.y += o.y; m2.z += o.z; m2.w += o.w;
                red[(b2 * 32 + hg) * 8 + c4] = m2;
            }
        }
        __syncthreads();
    }

    if (hg == 0) {
        #pragma unroll
        for (int b2 = 0; b2 < 8; ++b2) {
            float4 v = red[(b2 * 32) * 8 + c4];
            if (s == 0) {                  // bias term added exactly once per (b,x)
                const int ab = actions[b2];
                const float4 bi  = *(const float4*)(bias + x0 + c4 * 4);
                const float4 bav = *(const float4*)(ba + (size_t)ab * H + x0 + c4 * 4);
                v.x += bi.x * sigf(bav.x);
                v.y += bi.y * sigf(bav.y);
                v.z += bi.z * sigf(bav.z);
                v.w += bi.w * sigf(bav.w);
            }
            *(float4*)(Wyp + ((size_t)(b2 * 8 + s)) * H + x0 + c4 * 4) = v;
        }
    }
}

// Kernel 2: xWy[b,l] = sum_h x[b,l,h]*Wy[b,h] (+mask). Staging sums the 8 Wyp
// slots into LDS (Wyp is 512 KB, L2/L3-resident). 2048 blocks x 256 threads,
// 8 rows per block (2 per wave) -> 64 KB contiguous x per block.
__global__ __launch_bounds__(256) void k_xwy(
    const float* __restrict__ x, const float* __restrict__ Wyp,
    const unsigned char* __restrict__ mask, float* __restrict__ xWy)
{
    const int wave = threadIdx.x >> 6;
    const int lane = threadIdx.x & 63;
    const int row0 = blockIdx.x * 8;
    const int b    = row0 >> 11;                   // uniform per block

    __shared__ float wlds[H];                      // 8 KB
    for (int i = threadIdx.x * 4; i < H; i += 1024) {
        float4 sum = make_float4(0.f, 0.f, 0.f, 0.f);
        #pragma unroll
        for (int s = 0; s < 8; ++s) {
            const float4 v = *(const float4*)(Wyp + ((size_t)(b * 8 + s)) * H + i);
            sum.x += v.x; sum.y += v.y; sum.z += v.z; sum.w += v.w;
        }
        *(float4*)(wlds + i) = sum;
    }
    __syncthreads();

    #pragma unroll
    for (int r = 0; r < 2; ++r) {
        const int row = row0 + wave * 2 + r;
        const float* __restrict__ xb = x + (size_t)row * H;
        float acc = 0.f;
        #pragma unroll
        for (int j = 0; j < H / 256; ++j) {        // 8 iters
            const int off = j * 256 + lane * 4;
            const float4 xv = *(const float4*)(xb + off);
            const float4 wv = *(const float4*)(wlds + off);
            acc += xv.x * wv.x + xv.y * wv.y + xv.z * wv.z + xv.w * wv.w;
        }
        #pragma unroll
        for (int sh = 32; sh; sh >>= 1) acc += __shfl_xor(acc, sh, 64);
        if (lane == 0) xWy[row] = mask[row] ? NEG_INF : acc;
    }
}

// Kernel 3: softmax over L per batch row. grid: B blocks x 256 threads.
__global__ __launch_bounds__(256) void k_softmax(
    const float* __restrict__ xWy, float* __restrict__ out)
{
    const int b    = blockIdx.x;
    const int tid  = threadIdx.x;
    const int wave = tid >> 6;
    const int lane = tid & 63;
    const float* __restrict__ v = xWy + (size_t)b * L;

    float vals[L / 256];
    float m = -INFINITY;
    #pragma unroll
    for (int j = 0; j < L / 256; ++j) {
        vals[j] = v[tid + j * 256];
        m = fmaxf(m, vals[j]);
    }
    #pragma unroll
    for (int s = 32; s; s >>= 1) m = fmaxf(m, __shfl_xor(m, s, 64));

    __shared__ float redm[4];
    if (lane == 0) redm[wave] = m;
    __syncthreads();
    m = fmaxf(fmaxf(redm[0], redm[1]), fmaxf(redm[2], redm[3]));

    float sum = 0.f;
    #pragma unroll
    for (int j = 0; j < L / 256; ++j) {
        vals[j] = __expf(vals[j] - m);
        sum += vals[j];
    }
    #pragma unroll
    for (int s = 32; s; s >>= 1) sum += __shfl_xor(sum, s, 64);

    __shared__ float reds[4];
    if (lane == 0) reds[wave] = sum;
    __syncthreads();
    sum = reds[0] + reds[1] + reds[2] + reds[3];

    const float inv = 1.0f / sum;
    #pragma unroll
    for (int j = 0; j < L / 256; ++j)
        out[(size_t)b * L + tid + j * 256] = vals[j] * inv;
}

extern "C" void kernel_launch(void* const* d_in, const int* in_sizes, int n_in,
                              void* d_out, int out_size, void* d_ws, size_t ws_size,
                              hipStream_t stream) {
    const float*         x       = (const float*)d_in[0];
    const float*         y       = (const float*)d_in[1];
    const unsigned char* mask    = (const unsigned char*)d_in[2];
    const int*           actions = (const int*)d_in[3];
    const float*         weight  = (const float*)d_in[4];
    const float*         bias    = (const float*)d_in[5];
    const float*         wa      = (const float*)d_in[6];
    const float*         ba      = (const float*)d_in[7];
    float*               out     = (float*)d_out;

    float* ws  = (float*)d_ws;
    float* Wyp = ws;                           // B*8*H floats = 512 KB
    float* xWy = Wyp + (size_t)B * 8 * H;      // B*L floats

    dim3 g1(XT, 8);
    k_wy<<<g1, 256, 0, stream>>>(y, actions, weight, wa, bias, ba, Wyp);
    k_xwy<<<B * L / 8, 256, 0, stream>>>(x, Wyp, mask, xWy);
    k_softmax<<<B, 256, 0, stream>>>(xWy, out);
}

// Round 5
// 58.869 us; speedup vs baseline: 1.1933x; 1.1933x over previous
//
#include <hip/hip_runtime.h>
#include <hip/hip_bf16.h>
#include <math.h>

// Problem constants (match reference)
#define B 8
#define L 2048
#define H 2048
#define NA 8
#define NEG_INF (-1e30f)

#define XT 64          // blocks per b along x
#define COLS 32        // x-columns per block (8 float4)

typedef float vfloat4 __attribute__((ext_vector_type(4)));

__device__ __forceinline__ float sigf(float t) {
    // 1/(1+exp(-t)) with raw v_rcp_f32 (no IEEE div sequence).
    // |rel err| ~1e-7, fine vs 2e-2 threshold.
    return __builtin_amdgcn_rcpf(1.0f + __expf(-t));
}

// Kernel 1 (fused): Wy[b,x] = sum_h y[b,h]*weight[h,x]*sig(wa[a_b,h,x]) + bias[x]*sig(ba[a_b,x])
// grid (XT, B) = 512 blocks, 256 threads.
// Thread (hg = t>>3, c4 = t&7) accumulates rows h = hg, hg+32, ... for 4 cols;
// block-internal LDS tree reduce over the 32 h-groups (deterministic, no atomics).
// NOTE: duplicate wa[a] reads across b are deduped by the 256MiB L3 at run time —
// do NOT mark wa/weight non-temporal.
__global__ __launch_bounds__(256) void k_wy(
    const float* __restrict__ y, const int* __restrict__ actions,
    const float* __restrict__ weight, const float* __restrict__ wa,
    const float* __restrict__ bias, const float* __restrict__ ba,
    float* __restrict__ Wy)
{
    const int b  = blockIdx.y;
    const int x0 = blockIdx.x * COLS;
    const int a  = actions[b];
    const int c4 = threadIdx.x & 7;      // float4 column within block
    const int hg = threadIdx.x >> 3;     // 0..31

    __shared__ float ylds[H];            // 8 KB
    for (int i = threadIdx.x * 4; i < H; i += 1024)
        *(float4*)(ylds + i) = *(const float4*)(y + (size_t)b * H + i);
    __syncthreads();

    const float* __restrict__ wp = weight + x0 + c4 * 4;
    const float* __restrict__ ap = wa + (size_t)a * H * H + x0 + c4 * 4;

    float4 acc = make_float4(0.f, 0.f, 0.f, 0.f);
    #pragma unroll 8
    for (int h = hg; h < H; h += 32) {
        const float  yv = ylds[h];
        const float4 w4 = *(const float4*)(wp + (size_t)h * H);
        const float4 a4 = *(const float4*)(ap + (size_t)h * H);
        acc.x += yv * w4.x * sigf(a4.x);
        acc.y += yv * w4.y * sigf(a4.y);
        acc.z += yv * w4.z * sigf(a4.z);
        acc.w += yv * w4.w * sigf(a4.w);
    }

    __shared__ float4 red[32][8];        // 4 KB
    red[hg][c4] = acc;
    __syncthreads();
    #pragma unroll
    for (int s = 16; s; s >>= 1) {
        if (hg < s) {
            const float4 v = red[hg + s][c4];
            acc.x += v.x; acc.y += v.y; acc.z += v.z; acc.w += v.w;
            red[hg][c4] = acc;
        }
        __syncthreads();
    }

    if (hg == 0) {
        const float4 bi  = *(const float4*)(bias + x0 + c4 * 4);
        const float4 bav = *(const float4*)(ba + (size_t)a * H + x0 + c4 * 4);
        acc.x += bi.x * sigf(bav.x);
        acc.y += bi.y * sigf(bav.y);
        acc.z += bi.z * sigf(bav.z);
        acc.w += bi.w * sigf(bav.w);
        *(float4*)(Wy + (size_t)b * H + x0 + c4 * 4) = acc;
    }
}

// Kernel 2: xWy[b,l] = sum_h x[b,l,h]*Wy[b,h] (+mask). Wy staged in LDS.
// grid: B*L/8 = 2048 blocks x 256 threads; each wave owns 2 rows, processed
// INTERLEAVED (both loads in flight) for 2x memory-level parallelism.
// x is single-use -> non-temporal loads (evict-first, preserve L3 for wa/weight).
__global__ __launch_bounds__(256) void k_xwy(
    const float* __restrict__ x, const float* __restrict__ Wy,
    const unsigned char* __restrict__ mask, float* __restrict__ xWy)
{
    const int wave = threadIdx.x >> 6;
    const int lane = threadIdx.x & 63;
    const int row0 = blockIdx.x * 8;
    const int b    = row0 >> 11;                   // uniform per block

    __shared__ float wlds[H];                      // 8 KB
    for (int i = threadIdx.x * 4; i < H; i += 1024)
        *(float4*)(wlds + i) = *(const float4*)(Wy + (size_t)b * H + i);
    __syncthreads();

    const int rowA = row0 + wave * 2;
    const int rowB = rowA + 1;
    const vfloat4* __restrict__ xa = (const vfloat4*)(x + (size_t)rowA * H);
    const vfloat4* __restrict__ xb = (const vfloat4*)(x + (size_t)rowB * H);

    float accA = 0.f, accB = 0.f;
    #pragma unroll
    for (int j = 0; j < H / 256; ++j) {            // 8 iters
        const int off4 = j * 64 + lane;            // float4 index
        const vfloat4 va = __builtin_nontemporal_load(xa + off4);
        const vfloat4 vb = __builtin_nontemporal_load(xb + off4);
        const float4  wv = *(const float4*)(wlds + off4 * 4);
        accA += va.x * wv.x + va.y * wv.y + va.z * wv.z + va.w * wv.w;
        accB += vb.x * wv.x + vb.y * wv.y + vb.z * wv.z + vb.w * wv.w;
    }
    #pragma unroll
    for (int s = 32; s; s >>= 1) {
        accA += __shfl_xor(accA, s, 64);
        accB += __shfl_xor(accB, s, 64);
    }
    if (lane == 0) {
        xWy[rowA] = mask[rowA] ? NEG_INF : accA;
        xWy[rowB] = mask[rowB] ? NEG_INF : accB;
    }
}

// Kernel 3: softmax over L per batch row. grid: B blocks x 256 threads (8 elems/thread).
__global__ __launch_bounds__(256) void k_softmax(
    const float* __restrict__ xWy, float* __restrict__ out)
{
    const int b    = blockIdx.x;
    const int tid  = threadIdx.x;
    const int wave = tid >> 6;
    const int lane = tid & 63;
    const float* __restrict__ v = xWy + (size_t)b * L;

    float vals[L / 256];
    float m = -INFINITY;
    #pragma unroll
    for (int j = 0; j < L / 256; ++j) {
        vals[j] = v[tid + j * 256];
        m = fmaxf(m, vals[j]);
    }
    #pragma unroll
    for (int s = 32; s; s >>= 1) m = fmaxf(m, __shfl_xor(m, s, 64));

    __shared__ float redm[4];
    if (lane == 0) redm[wave] = m;
    __syncthreads();
    m = fmaxf(fmaxf(redm[0], redm[1]), fmaxf(redm[2], redm[3]));

    float sum = 0.f;
    #pragma unroll
    for (int j = 0; j < L / 256; ++j) {
        vals[j] = __expf(vals[j] - m);
        sum += vals[j];
    }
    #pragma unroll
    for (int s = 32; s; s >>= 1) sum += __shfl_xor(sum, s, 64);

    __shared__ float reds[4];
    if (lane == 0) reds[wave] = sum;
    __syncthreads();
    sum = reds[0] + reds[1] + reds[2] + reds[3];

    const float inv = 1.0f / sum;
    #pragma unroll
    for (int j = 0; j < L / 256; ++j)
        out[(size_t)b * L + tid + j * 256] = vals[j] * inv;
}

extern "C" void kernel_launch(void* const* d_in, const int* in_sizes, int n_in,
                              void* d_out, int out_size, void* d_ws, size_t ws_size,
                              hipStream_t stream) {
    const float*         x       = (const float*)d_in[0];
    const float*         y       = (const float*)d_in[1];
    const unsigned char* mask    = (const unsigned char*)d_in[2];
    const int*           actions = (const int*)d_in[3];
    const float*         weight  = (const float*)d_in[4];
    const float*         bias    = (const float*)d_in[5];
    const float*         wa      = (const float*)d_in[6];
    const float*         ba      = (const float*)d_in[7];
    float*               out     = (float*)d_out;

    float* ws  = (float*)d_ws;
    float* Wy  = ws;                        // B*H floats
    float* xWy = Wy + (size_t)B * H;        // B*L floats

    dim3 g1(XT, B);
    k_wy<<<g1, 256, 0, stream>>>(y, actions, weight, wa, bias, ba, Wy);
    k_xwy<<<B * L / 8, 256, 0, stream>>>(x, Wy, mask, xWy);
    k_softmax<<<B, 256, 0, stream>>>(xWy, out);
}

// Round 6
// 49.606 us; speedup vs baseline: 1.4162x; 1.1867x over previous
//
#include <hip/hip_runtime.h>
#include <hip/hip_bf16.h>
#include <math.h>

// Problem constants (match reference)
#define B 8
#define L 2048
#define H 2048
#define NA 8
#define NEG_INF (-1e30f)

#define XT 64          // column tiles per b (32 cols each)
#define COLS 32
#define HHALF (H / 2)  // 1024

__device__ __forceinline__ float sigf(float t) {
    // 1/(1+exp(-t)) with raw v_rcp_f32 (no IEEE div sequence). |rel err| ~1e-7.
    return __builtin_amdgcn_rcpf(1.0f + __expf(-t));
}

// Kernel 1: partial Wy. Wyp[b,hz,x] = sum_{h in half hz} y[b,h]*weight[h,x]*sig(wa[a_b,h,x])
//           (+ bias[x]*sig(ba[a_b,x]) folded into the hz==0 partial)
// grid (XT, B, 2) = 1024 blocks (4/CU, 16 waves/CU), 256 threads.
// Thread (hg = t>>3, c4 = t&7) strides 32 rows over its half; LDS tree reduce.
// No atomics/fences; wa re-reads across equal actions dedup in the 256MiB L3.
__global__ __launch_bounds__(256) void k_wy(
    const float* __restrict__ y, const int* __restrict__ actions,
    const float* __restrict__ weight, const float* __restrict__ wa,
    const float* __restrict__ bias, const float* __restrict__ ba,
    float* __restrict__ Wyp)
{
    const int b   = blockIdx.y;
    const int hz  = blockIdx.z;          // h-half 0/1
    const int x0  = blockIdx.x * COLS;
    const int a   = actions[b];
    const int c4  = threadIdx.x & 7;     // float4 column within block
    const int hg  = threadIdx.x >> 3;    // 0..31
    const int h0  = hz * HHALF;

    __shared__ float ylds[HHALF];        // 4 KB (exactly one 256-thread float4 pass)
    *(float4*)(ylds + threadIdx.x * 4) =
        *(const float4*)(y + (size_t)b * H + h0 + threadIdx.x * 4);
    __syncthreads();

    const float* __restrict__ wp = weight + (size_t)h0 * H + x0 + c4 * 4;
    const float* __restrict__ ap = wa + ((size_t)a * H + h0) * H + x0 + c4 * 4;

    float4 acc = make_float4(0.f, 0.f, 0.f, 0.f);
    #pragma unroll 8
    for (int h = hg; h < HHALF; h += 32) {         // 32 iterations
        const float  yv = ylds[h];
        const float4 w4 = *(const float4*)(wp + (size_t)h * H);
        const float4 a4 = *(const float4*)(ap + (size_t)h * H);
        acc.x += yv * w4.x * sigf(a4.x);
        acc.y += yv * w4.y * sigf(a4.y);
        acc.z += yv * w4.z * sigf(a4.z);
        acc.w += yv * w4.w * sigf(a4.w);
    }

    __shared__ float4 red[32][8];        // 4 KB
    red[hg][c4] = acc;
    __syncthreads();
    #pragma unroll
    for (int s = 16; s; s >>= 1) {
        if (hg < s) {
            const float4 v = red[hg + s][c4];
            acc.x += v.x; acc.y += v.y; acc.z += v.z; acc.w += v.w;
            red[hg][c4] = acc;
        }
        __syncthreads();
    }

    if (hg == 0) {
        if (hz == 0) {                   // bias term exactly once per (b,x)
            const float4 bi  = *(const float4*)(bias + x0 + c4 * 4);
            const float4 bav = *(const float4*)(ba + (size_t)a * H + x0 + c4 * 4);
            acc.x += bi.x * sigf(bav.x);
            acc.y += bi.y * sigf(bav.y);
            acc.z += bi.z * sigf(bav.z);
            acc.w += bi.w * sigf(bav.w);
        }
        *(float4*)(Wyp + ((size_t)(b * 2 + hz)) * H + x0 + c4 * 4) = acc;
    }
}

// Kernel 2: xWy[b,l] = sum_h x[b,l,h]*Wy[b,h] (+mask). One wave per row.
// Staging sums the 2 Wyp halves into LDS (128 KB total scratch, L2-resident).
// grid: B*L/4 = 4096 blocks x 256 threads (4 waves/block; block never straddles b).
__global__ __launch_bounds__(256) void k_xwy(
    const float* __restrict__ x, const float* __restrict__ Wyp,
    const unsigned char* __restrict__ mask, float* __restrict__ xWy)
{
    const int wave = threadIdx.x >> 6;
    const int lane = threadIdx.x & 63;
    const int row  = blockIdx.x * 4 + wave;        // 0..B*L-1
    const int b    = (blockIdx.x * 4) >> 11;       // uniform per block

    __shared__ float wlds[H];                      // 8 KB
    for (int i = threadIdx.x * 4; i < H; i += 1024) {
        const float4 v0 = *(const float4*)(Wyp + ((size_t)(b * 2 + 0)) * H + i);
        const float4 v1 = *(const float4*)(Wyp + ((size_t)(b * 2 + 1)) * H + i);
        float4 s; s.x = v0.x + v1.x; s.y = v0.y + v1.y;
        s.z = v0.z + v1.z; s.w = v0.w + v1.w;
        *(float4*)(wlds + i) = s;
    }
    __syncthreads();

    const float* __restrict__ xb = x + (size_t)row * H;

    float acc = 0.f;
    #pragma unroll
    for (int j = 0; j < H / 256; ++j) {            // 8 iters
        const int off = j * 256 + lane * 4;
        const float4 xv = *(const float4*)(xb + off);
        const float4 wv = *(const float4*)(wlds + off);
        acc += xv.x * wv.x + xv.y * wv.y + xv.z * wv.z + xv.w * wv.w;
    }
    #pragma unroll
    for (int s = 32; s; s >>= 1) acc += __shfl_xor(acc, s, 64);
    if (lane == 0) xWy[row] = mask[row] ? NEG_INF : acc;
}

// Kernel 3: softmax over L per batch row. grid: B blocks x 256 threads (8 elems/thread).
__global__ __launch_bounds__(256) void k_softmax(
    const float* __restrict__ xWy, float* __restrict__ out)
{
    const int b    = blockIdx.x;
    const int tid  = threadIdx.x;
    const int wave = tid >> 6;
    const int lane = tid & 63;
    const float* __restrict__ v = xWy + (size_t)b * L;

    float vals[L / 256];
    float m = -INFINITY;
    #pragma unroll
    for (int j = 0; j < L / 256; ++j) {
        vals[j] = v[tid + j * 256];
        m = fmaxf(m, vals[j]);
    }
    #pragma unroll
    for (int s = 32; s; s >>= 1) m = fmaxf(m, __shfl_xor(m, s, 64));

    __shared__ float redm[4];
    if (lane == 0) redm[wave] = m;
    __syncthreads();
    m = fmaxf(fmaxf(redm[0], redm[1]), fmaxf(redm[2], redm[3]));

    float sum = 0.f;
    #pragma unroll
    for (int j = 0; j < L / 256; ++j) {
        vals[j] = __expf(vals[j] - m);
        sum += vals[j];
    }
    #pragma unroll
    for (int s = 32; s; s >>= 1) sum += __shfl_xor(sum, s, 64);

    __shared__ float reds[4];
    if (lane == 0) reds[wave] = sum;
    __syncthreads();
    sum = reds[0] + reds[1] + reds[2] + reds[3];

    const float inv = 1.0f / sum;
    #pragma unroll
    for (int j = 0; j < L / 256; ++j)
        out[(size_t)b * L + tid + j * 256] = vals[j] * inv;
}

extern "C" void kernel_launch(void* const* d_in, const int* in_sizes, int n_in,
                              void* d_out, int out_size, void* d_ws, size_t ws_size,
                              hipStream_t stream) {
    const float*         x       = (const float*)d_in[0];
    const float*         y       = (const float*)d_in[1];
    const unsigned char* mask    = (const unsigned char*)d_in[2];
    const int*           actions = (const int*)d_in[3];
    const float*         weight  = (const float*)d_in[4];
    const float*         bias    = (const float*)d_in[5];
    const float*         wa      = (const float*)d_in[6];
    const float*         ba      = (const float*)d_in[7];
    float*               out     = (float*)d_out;

    float* ws  = (float*)d_ws;
    float* Wyp = ws;                           // B*2*H floats = 128 KB
    float* xWy = Wyp + (size_t)B * 2 * H;      // B*L floats

    dim3 g1(XT, B, 2);
    k_wy<<<g1, 256, 0, stream>>>(y, actions, weight, wa, bias, ba, Wyp);
    k_xwy<<<B * L / 4, 256, 0, stream>>>(x, Wyp, mask, xWy);
    k_softmax<<<B, 256, 0, stream>>>(xWy, out);
}